// Round 10
// baseline (62.463 us; speedup 1.0000x reference)
//
#include <hip/hip_runtime.h>
#include <hip/hip_bf16.h>
#include <stdint.h>

// Problem constants (fixed by setup_inputs): B=2, C=256, H=W=64, dg=4, K=3x3.
#define HW   4096
#define NB   2

typedef float f32x4 __attribute__((ext_vector_type(4)));
typedef short s16x8 __attribute__((ext_vector_type(8)));
typedef short s16x4 __attribute__((ext_vector_type(4)));

__device__ __forceinline__ unsigned short f2bf(float f) {
    // round-to-nearest-even f32 -> bf16
    union { float f; unsigned int u; } v; v.f = f;
    unsigned int u = v.u;
    unsigned int r = (u + 0x7FFFu + ((u >> 16) & 1u)) >> 16;
    return (unsigned short)r;
}

__device__ __forceinline__ float bf2f(unsigned short u) {
    union { unsigned int u; float f; } v; v.u = ((unsigned int)u) << 16;
    return v.f;
}

__device__ __forceinline__ unsigned int f2h(float f) {
    union { _Float16 h; unsigned short u; } v; v.h = (_Float16)f; return v.u;
}

__device__ __forceinline__ float h2f(unsigned int u) {
    union { unsigned short u; _Float16 h; } v; v.u = (unsigned short)u; return (float)v.h;
}

// ---------------------------------------------------------------------------
// K_prep: three independent prep stages in ONE dispatch.
//   blocks [0,1152)     : offset 1x1 conv + bilinear setup -> PACKED 16B params
//                         pbuf[loc] = {f16 w0..w3 | u16 row0..row3}
//   blocks [1152,2176)  : NCHW f32 -> NHWC bf16 transpose  (fbuf)
//   blocks [2176,2752)  : weights -> bf16 MFMA A-frag order (wfrag)
// ---------------------------------------------------------------------------
__global__ void __launch_bounds__(256)
k_prep(const float* __restrict__ pred, const float* __restrict__ wo,
       const float* __restrict__ regf, const float* __restrict__ clsf,
       const float* __restrict__ wr,   const float* __restrict__ wc,
       int4* __restrict__ pbuf,
       unsigned short* __restrict__ fbuf, unsigned short* __restrict__ wfrag) {
    int bb = blockIdx.x;
    if (bb < 1152) {
        // ---- params: loc = ((b*9+k)*4+g)*4096 + p ----
        int loc = bb * 256 + threadIdx.x;
        int p  = loc & 4095;
        int g  = (loc >> 12) & 3;
        int bk = loc >> 14;
        int b  = bk / 9;
        int k  = bk - b * 9;
        int rowy = ((g * 9 + k) * 2) * 34;
        float oy = 0.f, ox = 0.f;
        const float* pb = pred + (size_t)b * 34 * HW + p;
        #pragma unroll
        for (int c = 0; c < 34; ++c) {
            float pv = pb[c * HW];
            oy += wo[rowy + c]      * pv;
            ox += wo[rowy + 34 + c] * pv;
        }
        int h = p >> 6, w = p & 63;
        int ky = k / 3, kx = k - ky * 3;
        float py = oy + (float)(h + ky - 1);
        float px = ox + (float)(w + kx - 1);
        float fy0 = floorf(py), fx0 = floorf(px);
        int y0 = (int)fy0, x0 = (int)fx0;
        float fy = py - fy0, fx = px - fx0;
        float wy0 = 1.f - fy, wy1 = fy, wx0 = 1.f - fx, wx1 = fx;
        if (!(y0 >= 0  && y0 <= 63)) wy0 = 0.f;
        if (!(y0 >= -1 && y0 <= 62)) wy1 = 0.f;
        if (!(x0 >= 0  && x0 <= 63)) wx0 = 0.f;
        if (!(x0 >= -1 && x0 <= 62)) wx1 = 0.f;
        int cy0 = min(max(y0, 0), 63),     cy1 = min(max(y0 + 1, 0), 63);
        int cx0 = min(max(x0, 0), 63),     cx1 = min(max(x0 + 1, 0), 63);
        int r0 = cy0 * 64 + cx0, r1 = cy0 * 64 + cx1;
        int r2 = cy1 * 64 + cx0, r3 = cy1 * 64 + cx1;
        int4 pk;
        pk.x = (int)(f2h(wy0 * wx0) | (f2h(wy0 * wx1) << 16));
        pk.y = (int)(f2h(wy1 * wx0) | (f2h(wy1 * wx1) << 16));
        pk.z = (int)((unsigned)r0 | ((unsigned)r1 << 16));
        pk.w = (int)((unsigned)r2 | ((unsigned)r3 << 16));
        pbuf[loc] = pk;
    } else if (bb < 2176) {
        // ---- NCHW f32 -> NHWC bf16 ----
        __shared__ float tile[64][65];
        int bid = bb - 1152;
        int pt = bid & 63;
        int cb = (bid >> 6) & 3;
        int b  = (bid >> 8) & 1;
        int cv = bid >> 9;
        const float* src = cv ? clsf : regf;
        int t = threadIdx.x;
        int pl = t & 63, q = t >> 6;
        #pragma unroll
        for (int i = 0; i < 16; ++i) {
            int cl = q + i * 4;
            tile[cl][pl] = src[((size_t)(b * 256 + cb * 64 + cl)) * HW + pt * 64 + pl];
        }
        __syncthreads();
        int cpair = t & 31, prow = t >> 5;
        #pragma unroll
        for (int i = 0; i < 8; ++i) {
            int p = i * 8 + prow;
            unsigned int u0 = f2bf(tile[cpair * 2][p]);
            unsigned int u1 = f2bf(tile[cpair * 2 + 1][p]);
            *(unsigned int*)&fbuf[((size_t)((cv * 2 + b) * HW + pt * 64 + p)) * 256
                                  + cb * 64 + cpair * 2] = u0 | (u1 << 16);
        }
    } else {
        // ---- weights -> A-frag: L = conv*73728 + ((s*2+kk)*16+ot)*64+lane ----
        int L = (bb - 2176) * 256 + threadIdx.x;
        int conv = L / 73728;
        int r = L - conv * 73728;
        int lane = r & 63;
        int ot = (r >> 6) & 15;
        int kk = (r >> 10) & 1;
        int s  = r >> 11;
        int k = s >> 2, g = s & 3;
        int o  = ot * 16 + (lane & 15);
        int cb = kk * 32 + (lane >> 4) * 8;
        const float* w = conv ? wc : wr;
        s16x8 v;
        #pragma unroll
        for (int j = 0; j < 8; ++j) {
            int c = cb + j;
            v[j] = (short)f2bf(w[((size_t)o * 256 + g * 64 + c) * 9 + k]);
        }
        *(s16x8*)(wfrag + (size_t)L * 8) = v;
    }
}

// ---------------------------------------------------------------------------
// K_main: fused implicit GEMM, 256 blocks x 1024 threads (16 waves, 4/SIMD).
// Same tile as R5/R9 (BM=256 Cout, BN=64 px) -> identical VMEM traffic, 2x the
// wave pool so VALU/LDS/MFMA overlap under the ~1050 line/step VMEM stream.
//   build: px = tid>>4 (0..63), cg = tid&15 (4-ch granule, 8B gathers)
//   wave wv (0..15): 16 Cout x 64 px, acc[4] (np), 8 MFMA/step
//   pipeline: gathers(s+2)+ldpar(s+3) before a raw s_barrier (lgkmcnt-only
//   drain); domfma(s); loadA(s+1) (in-place prefetch); finish(s+1).
// ---------------------------------------------------------------------------
__global__ void __launch_bounds__(1024, 4)
k_main(const int4* __restrict__ pbuf,
       const unsigned short* __restrict__ fbuf, const unsigned short* __restrict__ wfrag,
       float* __restrict__ out) {
    __shared__ __align__(16) unsigned short vt[2][64][72];   // 64 px x 64 ch + pad

    int bid0 = blockIdx.x;
    int bid = (bid0 & 7) * 32 + (bid0 >> 3);       // XCD-contiguous swizzle (256%8==0)
    int conv = bid >> 7;
    int b    = (bid >> 6) & 1;
    int pt   = bid & 63;
    int p0   = pt * 64;

    int tid  = threadIdx.x;
    int lane = tid & 63;
    int wv   = tid >> 6;                           // wave id 0..15 = Cout 16-block
    int px   = tid >> 4;                           // build: pixel 0..63
    int cg   = tid & 15;                           // build: channel granule (4 ch)

    const char* fbb = (const char*)(fbuf + (size_t)(conv * 2 + b) * HW * 256) + cg * 8;
    const unsigned short* wfc = wfrag + (size_t)conv * 73728 * 8;
    const int4* pbb = pbuf + (size_t)b * 9 * 4 * HW + p0 + px;

    f32x4 acc[4];
    #pragma unroll
    for (int j = 0; j < 4; ++j) acc[j] = (f32x4){0.f, 0.f, 0.f, 0.f};

    struct Gat { s16x4 a, b, c, d; };

    auto ldpar = [&](int s) -> int4 {
        int k = s >> 2, g = s & 3;
        return pbb[(k * 4 + g) * HW];
    };

    auto gather = [&](const int4& P, int g) -> Gat {
        const char* base = fbb + g * 128;
        int o0 = ((unsigned)P.z & 0xffffu) << 9;
        int o1 = ((unsigned)P.z >> 16) << 9;
        int o2 = ((unsigned)P.w & 0xffffu) << 9;
        int o3 = ((unsigned)P.w >> 16) << 9;
        Gat G;
        G.a = *(const s16x4*)(base + o0);
        G.b = *(const s16x4*)(base + o1);
        G.c = *(const s16x4*)(base + o2);
        G.d = *(const s16x4*)(base + o3);
        return G;
    };

    auto finish = [&](const int4& P, const Gat& G, int buf) {
        float w0 = h2f((unsigned)P.x & 0xffffu), w1 = h2f((unsigned)P.x >> 16);
        float w2 = h2f((unsigned)P.y & 0xffffu), w3 = h2f((unsigned)P.y >> 16);
        s16x4 pk;
        #pragma unroll
        for (int j = 0; j < 4; ++j) {
            float r = w0 * bf2f((unsigned short)G.a[j])
                    + w1 * bf2f((unsigned short)G.b[j])
                    + w2 * bf2f((unsigned short)G.c[j])
                    + w3 * bf2f((unsigned short)G.d[j]);
            pk[j] = (short)f2bf(r);
        }
        *(s16x4*)&vt[buf][px][cg * 4] = pk;
    };

    // A-fragments: 2 per wave (kk=0,1); prefetched in place one step ahead.
    s16x8 af0, af1;
    auto loadA = [&](int s) {
        const unsigned short* wfs = wfc + (size_t)s * 2048 * 8;
        af0 = *(const s16x8*)(wfs + ((size_t)( 0 + wv) * 64 + lane) * 8);
        af1 = *(const s16x8*)(wfs + ((size_t)(16 + wv) * 64 + lane) * 8);
    };

    auto domfma = [&](int s) {
        s16x8 bfr[4];
        #pragma unroll
        for (int np = 0; np < 4; ++np)
            bfr[np] = *(const s16x8*)
                &vt[s & 1][np * 16 + (lane & 15)][(lane >> 4) * 8];          // kk=0
        #pragma unroll
        for (int np = 0; np < 4; ++np)
            acc[np] = __builtin_amdgcn_mfma_f32_16x16x32_bf16(af0, bfr[np],
                                                              acc[np], 0, 0, 0);
        #pragma unroll
        for (int np = 0; np < 4; ++np)
            bfr[np] = *(const s16x8*)
                &vt[s & 1][np * 16 + (lane & 15)][32 + (lane >> 4) * 8];     // kk=1
        #pragma unroll
        for (int np = 0; np < 4; ++np)
            acc[np] = __builtin_amdgcn_mfma_f32_16x16x32_bf16(af1, bfr[np],
                                                              acc[np], 0, 0, 0);
    };

    // ---- software pipeline (gathers 2 steps deep) ----
    loadA(0);
    int4 P0 = ldpar(0);
    Gat G0 = gather(P0, 0);
    finish(P0, G0, 0);                  // vt[0]
    int4 P1 = ldpar(1);                 // par(s+1)
    int4 P2 = ldpar(2);                 // par(s+2)
    Gat G1 = gather(P1, 1);             // gathers for step 1 (used at iter 0)

    for (int s = 0; s < 36; ++s) {
        Gat Gn;                          // gathers for step s+2
        int4 Pn;
        if (s + 2 < 36) Gn = gather(P2, (s + 2) & 3);
        Pn = (s + 3 < 36) ? ldpar(s + 3) : P2;
        asm volatile("s_waitcnt lgkmcnt(0)" ::: "memory"); // vt writes visible
        __builtin_amdgcn_s_barrier();                      // vmcnt NOT drained
        domfma(s);                       // pure LDS + MFMA (af prefetched)
        if (s + 1 < 36) {
            loadA(s + 1);                // af used by domfma(s) already
            finish(P1, G1, (s + 1) & 1); // G1 issued at iter s-1: landed
        }
        P1 = P2; P2 = Pn; G1 = Gn;
    }

    // epilogue: C/D layout col = lane&15 (pixel), row = (lane>>4)*4 + reg (o)
    float* ob = out + (size_t)conv * (NB * 256 * HW) + (size_t)b * 256 * HW;
    #pragma unroll
    for (int np = 0; np < 4; ++np)
        #pragma unroll
        for (int r = 0; r < 4; ++r) {
            int o = wv * 16 + (lane >> 4) * 4 + r;
            int p = p0 + np * 16 + (lane & 15);
            float v = acc[np][r];
            ob[(size_t)o * HW + p] = v > 0.f ? v : 0.f;
        }
}

// ---------------------------------------------------------------------------
// ws layout (bytes):
//   [0,        4718592)  pbuf  : 294912 int4 (packed params)
//   [4718592, 13107200)  fbuf  : 4*4096*256 bf16 NHWC
//   [13107200,15466496)  wfrag : 2*73728*8 bf16
// requires ws_size >= 15466496
// ---------------------------------------------------------------------------
extern "C" void kernel_launch(void* const* d_in, const int* in_sizes, int n_in,
                              void* d_out, int out_size, void* d_ws, size_t ws_size,
                              hipStream_t stream) {
    (void)in_sizes; (void)n_in; (void)out_size; (void)ws_size;
    const float* reg_feat = (const float*)d_in[0];
    const float* cls_feat = (const float*)d_in[1];
    const float* pred     = (const float*)d_in[2];
    const float* w_off    = (const float*)d_in[3];
    const float* w_reg    = (const float*)d_in[4];
    const float* w_cls    = (const float*)d_in[5];
    float* out = (float*)d_out;
    char* ws = (char*)d_ws;
    int4*           pbuf  = (int4*)ws;
    unsigned short* fbuf  = (unsigned short*)(ws + 4718592);
    unsigned short* wfrag = (unsigned short*)(ws + 13107200);

    k_prep<<<2752, 256, 0, stream>>>(pred, w_off, reg_feat, cls_feat, w_reg, w_cls,
                                     pbuf, fbuf, wfrag);
    k_main<<< 256, 1024, 0, stream>>>(pbuf, fbuf, wfrag, out);
}

// Round 11
// 59.105 us; speedup vs baseline: 1.0568x; 1.0568x over previous
//
#include <hip/hip_runtime.h>
#include <hip/hip_bf16.h>
#include <stdint.h>

// Problem constants (fixed by setup_inputs): B=2, C=256, H=W=64, dg=4, K=3x3.
#define HW   4096
#define NB   2

typedef float f32x4 __attribute__((ext_vector_type(4)));
typedef short s16x8 __attribute__((ext_vector_type(8)));
typedef short s16x4 __attribute__((ext_vector_type(4)));

__device__ __forceinline__ unsigned short f2bf(float f) {
    // round-to-nearest-even f32 -> bf16
    union { float f; unsigned int u; } v; v.f = f;
    unsigned int u = v.u;
    unsigned int r = (u + 0x7FFFu + ((u >> 16) & 1u)) >> 16;
    return (unsigned short)r;
}

__device__ __forceinline__ float bf2f(unsigned short u) {
    union { unsigned int u; float f; } v; v.u = ((unsigned int)u) << 16;
    return v.f;
}

__device__ __forceinline__ unsigned int f2h(float f) {
    union { _Float16 h; unsigned short u; } v; v.h = (_Float16)f; return v.u;
}

__device__ __forceinline__ float h2f(unsigned int u) {
    union { unsigned short u; _Float16 h; } v; v.u = (unsigned short)u; return (float)v.h;
}

// ---------------------------------------------------------------------------
// K_prep: three independent prep stages in ONE dispatch (unchanged from R10).
//   blocks [0,1152)     : offset 1x1 conv + bilinear setup -> PACKED 16B params
//   blocks [1152,2176)  : NCHW f32 -> NHWC bf16 transpose  (fbuf)
//   blocks [2176,2752)  : weights -> bf16 MFMA A-frag order (wfrag)
// ---------------------------------------------------------------------------
__global__ void __launch_bounds__(256)
k_prep(const float* __restrict__ pred, const float* __restrict__ wo,
       const float* __restrict__ regf, const float* __restrict__ clsf,
       const float* __restrict__ wr,   const float* __restrict__ wc,
       int4* __restrict__ pbuf,
       unsigned short* __restrict__ fbuf, unsigned short* __restrict__ wfrag) {
    int bb = blockIdx.x;
    if (bb < 1152) {
        // ---- params: loc = ((b*9+k)*4+g)*4096 + p ----
        int loc = bb * 256 + threadIdx.x;
        int p  = loc & 4095;
        int g  = (loc >> 12) & 3;
        int bk = loc >> 14;
        int b  = bk / 9;
        int k  = bk - b * 9;
        int rowy = ((g * 9 + k) * 2) * 34;
        float oy = 0.f, ox = 0.f;
        const float* pb = pred + (size_t)b * 34 * HW + p;
        #pragma unroll
        for (int c = 0; c < 34; ++c) {
            float pv = pb[c * HW];
            oy += wo[rowy + c]      * pv;
            ox += wo[rowy + 34 + c] * pv;
        }
        int h = p >> 6, w = p & 63;
        int ky = k / 3, kx = k - ky * 3;
        float py = oy + (float)(h + ky - 1);
        float px = ox + (float)(w + kx - 1);
        float fy0 = floorf(py), fx0 = floorf(px);
        int y0 = (int)fy0, x0 = (int)fx0;
        float fy = py - fy0, fx = px - fx0;
        float wy0 = 1.f - fy, wy1 = fy, wx0 = 1.f - fx, wx1 = fx;
        if (!(y0 >= 0  && y0 <= 63)) wy0 = 0.f;
        if (!(y0 >= -1 && y0 <= 62)) wy1 = 0.f;
        if (!(x0 >= 0  && x0 <= 63)) wx0 = 0.f;
        if (!(x0 >= -1 && x0 <= 62)) wx1 = 0.f;
        int cy0 = min(max(y0, 0), 63),     cy1 = min(max(y0 + 1, 0), 63);
        int cx0 = min(max(x0, 0), 63),     cx1 = min(max(x0 + 1, 0), 63);
        int r0 = cy0 * 64 + cx0, r1 = cy0 * 64 + cx1;
        int r2 = cy1 * 64 + cx0, r3 = cy1 * 64 + cx1;
        int4 pk;
        pk.x = (int)(f2h(wy0 * wx0) | (f2h(wy0 * wx1) << 16));
        pk.y = (int)(f2h(wy1 * wx0) | (f2h(wy1 * wx1) << 16));
        pk.z = (int)((unsigned)r0 | ((unsigned)r1 << 16));
        pk.w = (int)((unsigned)r2 | ((unsigned)r3 << 16));
        pbuf[loc] = pk;
    } else if (bb < 2176) {
        // ---- NCHW f32 -> NHWC bf16 ----
        __shared__ float tile[64][65];
        int bid = bb - 1152;
        int pt = bid & 63;
        int cb = (bid >> 6) & 3;
        int b  = (bid >> 8) & 1;
        int cv = bid >> 9;
        const float* src = cv ? clsf : regf;
        int t = threadIdx.x;
        int pl = t & 63, q = t >> 6;
        #pragma unroll
        for (int i = 0; i < 16; ++i) {
            int cl = q + i * 4;
            tile[cl][pl] = src[((size_t)(b * 256 + cb * 64 + cl)) * HW + pt * 64 + pl];
        }
        __syncthreads();
        int cpair = t & 31, prow = t >> 5;
        #pragma unroll
        for (int i = 0; i < 8; ++i) {
            int p = i * 8 + prow;
            unsigned int u0 = f2bf(tile[cpair * 2][p]);
            unsigned int u1 = f2bf(tile[cpair * 2 + 1][p]);
            *(unsigned int*)&fbuf[((size_t)((cv * 2 + b) * HW + pt * 64 + p)) * 256
                                  + cb * 64 + cpair * 2] = u0 | (u1 << 16);
        }
    } else {
        // ---- weights -> A-frag: L = conv*73728 + ((s*2+kk)*16+ot)*64+lane ----
        int L = (bb - 2176) * 256 + threadIdx.x;
        int conv = L / 73728;
        int r = L - conv * 73728;
        int lane = r & 63;
        int ot = (r >> 6) & 15;
        int kk = (r >> 10) & 1;
        int s  = r >> 11;
        int k = s >> 2, g = s & 3;
        int o  = ot * 16 + (lane & 15);
        int cb = kk * 32 + (lane >> 4) * 8;
        const float* w = conv ? wc : wr;
        s16x8 v;
        #pragma unroll
        for (int j = 0; j < 8; ++j) {
            int c = cb + j;
            v[j] = (short)f2bf(w[((size_t)o * 256 + g * 64 + c) * 9 + k]);
        }
        *(s16x8*)(wfrag + (size_t)L * 8) = v;
    }
}

// ---------------------------------------------------------------------------
// K_main: fused implicit GEMM, 256 blocks x 1024 threads (16 waves, 4/SIMD).
// R11: wave grid split along kk (the reduction), NOT Cout/px, so per-step
// traffic is IDENTICAL to R9 (B-reads 64xb128, A 32KB, gathers 512 lines)
// while waves/SIMD doubles 2->4.
//   wave wv = (cw 0..7) x (kh 0..1): 32 Cout x 64 px x kk=kh half; acc[2][4];
//   8 MFMA/step. kk-halves combined in an LDS reduction epilogue.
//   build: px = tid>>4 (0..63), cg = tid&15 (4-ch granule, 8B gathers).
//   pipeline: gathers(s+2)+ldpar(s+3) before a raw s_barrier (lgkmcnt-only
//   drain, vmcnt in flight); domfma(s); loadA(s+1); finish(s+1).
// ---------------------------------------------------------------------------
__global__ void __launch_bounds__(1024, 4)
k_main(const int4* __restrict__ pbuf,
       const unsigned short* __restrict__ fbuf, const unsigned short* __restrict__ wfrag,
       float* __restrict__ out) {
    __shared__ __align__(16) unsigned short vt[2][64][72];   // 64 px x 64 ch + pad
    __shared__ __align__(16) f32x4 red[8][64];               // kk-reduction buffer

    int bid0 = blockIdx.x;
    int bid = (bid0 & 7) * 32 + (bid0 >> 3);       // XCD-contiguous swizzle (256%8==0)
    int conv = bid >> 7;
    int b    = (bid >> 6) & 1;
    int pt   = bid & 63;
    int p0   = pt * 64;

    int tid  = threadIdx.x;
    int lane = tid & 63;
    int wv   = tid >> 6;                           // wave id 0..15
    int cw   = wv >> 1;                            // Cout group (8 x 32)
    int kh   = wv & 1;                             // kk half (0,1)
    int px   = tid >> 4;                           // build: pixel 0..63
    int cg   = tid & 15;                           // build: channel granule (4 ch)

    const char* fbb = (const char*)(fbuf + (size_t)(conv * 2 + b) * HW * 256) + cg * 8;
    const unsigned short* wfc = wfrag + (size_t)conv * 73728 * 8;
    const int4* pbb = pbuf + (size_t)b * 9 * 4 * HW + p0 + px;

    f32x4 acc[2][4];                               // [mo][np], kk = kh only
    #pragma unroll
    for (int i = 0; i < 2; ++i)
        #pragma unroll
        for (int j = 0; j < 4; ++j)
            acc[i][j] = (f32x4){0.f, 0.f, 0.f, 0.f};

    struct Gat { s16x4 a, b, c, d; };

    auto ldpar = [&](int s) -> int4 {
        int k = s >> 2, g = s & 3;
        return pbb[(k * 4 + g) * HW];
    };

    auto gather = [&](const int4& P, int g) -> Gat {
        const char* base = fbb + g * 128;
        int o0 = ((unsigned)P.z & 0xffffu) << 9;
        int o1 = ((unsigned)P.z >> 16) << 9;
        int o2 = ((unsigned)P.w & 0xffffu) << 9;
        int o3 = ((unsigned)P.w >> 16) << 9;
        Gat G;
        G.a = *(const s16x4*)(base + o0);
        G.b = *(const s16x4*)(base + o1);
        G.c = *(const s16x4*)(base + o2);
        G.d = *(const s16x4*)(base + o3);
        return G;
    };

    auto finish = [&](const int4& P, const Gat& G, int buf) {
        float w0 = h2f((unsigned)P.x & 0xffffu), w1 = h2f((unsigned)P.x >> 16);
        float w2 = h2f((unsigned)P.y & 0xffffu), w3 = h2f((unsigned)P.y >> 16);
        s16x4 pk;
        #pragma unroll
        for (int j = 0; j < 4; ++j) {
            float r = w0 * bf2f((unsigned short)G.a[j])
                    + w1 * bf2f((unsigned short)G.b[j])
                    + w2 * bf2f((unsigned short)G.c[j])
                    + w3 * bf2f((unsigned short)G.d[j]);
            pk[j] = (short)f2bf(r);
        }
        *(s16x4*)&vt[buf][px][cg * 4] = pk;
    };

    // A-fragments: 2 per wave (mo=0,1 of its kk-half); prefetched in place.
    s16x8 af0, af1;
    auto loadA = [&](int s) {
        const unsigned short* wfs = wfc + (size_t)s * 2048 * 8;
        af0 = *(const s16x8*)(wfs + ((size_t)(kh * 16 + cw * 2 + 0) * 64 + lane) * 8);
        af1 = *(const s16x8*)(wfs + ((size_t)(kh * 16 + cw * 2 + 1) * 64 + lane) * 8);
    };

    auto domfma = [&](int s) {
        #pragma unroll
        for (int np = 0; np < 4; ++np) {
            s16x8 bfr = *(const s16x8*)
                &vt[s & 1][np * 16 + (lane & 15)][kh * 32 + (lane >> 4) * 8];
            acc[0][np] = __builtin_amdgcn_mfma_f32_16x16x32_bf16(af0, bfr,
                                                                 acc[0][np], 0, 0, 0);
            acc[1][np] = __builtin_amdgcn_mfma_f32_16x16x32_bf16(af1, bfr,
                                                                 acc[1][np], 0, 0, 0);
        }
    };

    // ---- software pipeline (gathers 2 steps deep) ----
    loadA(0);
    int4 P0 = ldpar(0);
    Gat G0 = gather(P0, 0);
    finish(P0, G0, 0);                  // vt[0]
    int4 P1 = ldpar(1);                 // par(s+1)
    int4 P2 = ldpar(2);                 // par(s+2)
    Gat G1 = gather(P1, 1);             // gathers for step 1 (used at iter 0)

    for (int s = 0; s < 36; ++s) {
        Gat Gn;                          // gathers for step s+2
        int4 Pn;
        if (s + 2 < 36) Gn = gather(P2, (s + 2) & 3);
        Pn = (s + 3 < 36) ? ldpar(s + 3) : P2;
        asm volatile("s_waitcnt lgkmcnt(0)" ::: "memory"); // vt writes visible
        __builtin_amdgcn_s_barrier();                      // vmcnt NOT drained
        domfma(s);                       // pure LDS + MFMA (af prefetched)
        if (s + 1 < 36) {
            loadA(s + 1);                // af used by domfma(s) already
            finish(P1, G1, (s + 1) & 1); // G1 issued at iter s-1: landed
        }
        P1 = P2; P2 = Pn; G1 = Gn;
    }

    // ---- epilogue: combine kk-halves via LDS, ReLU, store ----
    // C/D layout: col = lane&15 (pixel), row = (lane>>4)*4 + reg (Cout)
    float* ob = out + (size_t)conv * (NB * 256 * HW) + (size_t)b * 256 * HW;
    #pragma unroll
    for (int mo = 0; mo < 2; ++mo)
        #pragma unroll
        for (int np = 0; np < 4; ++np) {
            __syncthreads();                       // red free from previous chunk
            if (kh == 1) red[cw][lane] = acc[mo][np];
            __syncthreads();
            if (kh == 0) {
                f32x4 o4 = red[cw][lane];
                #pragma unroll
                for (int r = 0; r < 4; ++r) {
                    int o = cw * 32 + mo * 16 + (lane >> 4) * 4 + r;
                    int p = p0 + np * 16 + (lane & 15);
                    float v = acc[mo][np][r] + o4[r];
                    ob[(size_t)o * HW + p] = v > 0.f ? v : 0.f;
                }
            }
        }
}

// ---------------------------------------------------------------------------
// ws layout (bytes):
//   [0,        4718592)  pbuf  : 294912 int4 (packed params)
//   [4718592, 13107200)  fbuf  : 4*4096*256 bf16 NHWC
//   [13107200,15466496)  wfrag : 2*73728*8 bf16
// requires ws_size >= 15466496
// ---------------------------------------------------------------------------
extern "C" void kernel_launch(void* const* d_in, const int* in_sizes, int n_in,
                              void* d_out, int out_size, void* d_ws, size_t ws_size,
                              hipStream_t stream) {
    (void)in_sizes; (void)n_in; (void)out_size; (void)ws_size;
    const float* reg_feat = (const float*)d_in[0];
    const float* cls_feat = (const float*)d_in[1];
    const float* pred     = (const float*)d_in[2];
    const float* w_off    = (const float*)d_in[3];
    const float* w_reg    = (const float*)d_in[4];
    const float* w_cls    = (const float*)d_in[5];
    float* out = (float*)d_out;
    char* ws = (char*)d_ws;
    int4*           pbuf  = (int4*)ws;
    unsigned short* fbuf  = (unsigned short*)(ws + 4718592);
    unsigned short* wfrag = (unsigned short*)(ws + 13107200);

    k_prep<<<2752, 256, 0, stream>>>(pred, w_off, reg_feat, cls_feat, w_reg, w_cls,
                                     pbuf, fbuf, wfrag);
    k_main<<< 256, 1024, 0, stream>>>(pbuf, fbuf, wfrag, out);
}

// Round 12
// 50.041 us; speedup vs baseline: 1.2482x; 1.1811x over previous
//
#include <hip/hip_runtime.h>
#include <hip/hip_bf16.h>
#include <stdint.h>

// Problem constants (fixed by setup_inputs): B=2, C=256, H=W=64, dg=4, K=3x3.
#define HW   4096
#define NB   2

typedef float f32x4 __attribute__((ext_vector_type(4)));
typedef short s16x8 __attribute__((ext_vector_type(8)));
typedef short s16x4 __attribute__((ext_vector_type(4)));

__device__ __forceinline__ unsigned short f2bf(float f) {
    // round-to-nearest-even f32 -> bf16
    union { float f; unsigned int u; } v; v.f = f;
    unsigned int u = v.u;
    unsigned int r = (u + 0x7FFFu + ((u >> 16) & 1u)) >> 16;
    return (unsigned short)r;
}

__device__ __forceinline__ float bf2f(unsigned short u) {
    union { unsigned int u; float f; } v; v.u = ((unsigned int)u) << 16;
    return v.f;
}

__device__ __forceinline__ unsigned int f2h(float f) {
    union { _Float16 h; unsigned short u; } v; v.h = (_Float16)f; return v.u;
}

__device__ __forceinline__ float h2f(unsigned int u) {
    union { unsigned short u; _Float16 h; } v; v.u = (unsigned short)u; return (float)v.h;
}

// Step order (R12): g-major so 9 consecutive steps share one g channel-slice
// (L1 reuse of the gather working set). g = s/9, k = s%9.

// ---------------------------------------------------------------------------
// K_prep: three independent prep stages in ONE dispatch.
//   blocks [0,1152)     : offset 1x1 conv + bilinear setup -> PACKED 16B params
//   blocks [1152,2176)  : NCHW f32 -> NHWC bf16 transpose  (fbuf)
//   blocks [2176,2752)  : weights -> bf16 MFMA A-frag order (wfrag, g-major s)
// ---------------------------------------------------------------------------
__global__ void __launch_bounds__(256)
k_prep(const float* __restrict__ pred, const float* __restrict__ wo,
       const float* __restrict__ regf, const float* __restrict__ clsf,
       const float* __restrict__ wr,   const float* __restrict__ wc,
       int4* __restrict__ pbuf,
       unsigned short* __restrict__ fbuf, unsigned short* __restrict__ wfrag) {
    int bb = blockIdx.x;
    if (bb < 1152) {
        // ---- params: loc = ((b*9+k)*4+g)*4096 + p ----
        int loc = bb * 256 + threadIdx.x;
        int p  = loc & 4095;
        int g  = (loc >> 12) & 3;
        int bk = loc >> 14;
        int b  = bk / 9;
        int k  = bk - b * 9;
        int rowy = ((g * 9 + k) * 2) * 34;
        float oy = 0.f, ox = 0.f;
        const float* pb = pred + (size_t)b * 34 * HW + p;
        #pragma unroll
        for (int c = 0; c < 34; ++c) {
            float pv = pb[c * HW];
            oy += wo[rowy + c]      * pv;
            ox += wo[rowy + 34 + c] * pv;
        }
        int h = p >> 6, w = p & 63;
        int ky = k / 3, kx = k - ky * 3;
        float py = oy + (float)(h + ky - 1);
        float px = ox + (float)(w + kx - 1);
        float fy0 = floorf(py), fx0 = floorf(px);
        int y0 = (int)fy0, x0 = (int)fx0;
        float fy = py - fy0, fx = px - fx0;
        float wy0 = 1.f - fy, wy1 = fy, wx0 = 1.f - fx, wx1 = fx;
        if (!(y0 >= 0  && y0 <= 63)) wy0 = 0.f;
        if (!(y0 >= -1 && y0 <= 62)) wy1 = 0.f;
        if (!(x0 >= 0  && x0 <= 63)) wx0 = 0.f;
        if (!(x0 >= -1 && x0 <= 62)) wx1 = 0.f;
        int cy0 = min(max(y0, 0), 63),     cy1 = min(max(y0 + 1, 0), 63);
        int cx0 = min(max(x0, 0), 63),     cx1 = min(max(x0 + 1, 0), 63);
        int r0 = cy0 * 64 + cx0, r1 = cy0 * 64 + cx1;
        int r2 = cy1 * 64 + cx0, r3 = cy1 * 64 + cx1;
        int4 pk;
        pk.x = (int)(f2h(wy0 * wx0) | (f2h(wy0 * wx1) << 16));
        pk.y = (int)(f2h(wy1 * wx0) | (f2h(wy1 * wx1) << 16));
        pk.z = (int)((unsigned)r0 | ((unsigned)r1 << 16));
        pk.w = (int)((unsigned)r2 | ((unsigned)r3 << 16));
        pbuf[loc] = pk;
    } else if (bb < 2176) {
        // ---- NCHW f32 -> NHWC bf16 ----
        __shared__ float tile[64][65];
        int bid = bb - 1152;
        int pt = bid & 63;
        int cb = (bid >> 6) & 3;
        int b  = (bid >> 8) & 1;
        int cv = bid >> 9;
        const float* src = cv ? clsf : regf;
        int t = threadIdx.x;
        int pl = t & 63, q = t >> 6;
        #pragma unroll
        for (int i = 0; i < 16; ++i) {
            int cl = q + i * 4;
            tile[cl][pl] = src[((size_t)(b * 256 + cb * 64 + cl)) * HW + pt * 64 + pl];
        }
        __syncthreads();
        int cpair = t & 31, prow = t >> 5;
        #pragma unroll
        for (int i = 0; i < 8; ++i) {
            int p = i * 8 + prow;
            unsigned int u0 = f2bf(tile[cpair * 2][p]);
            unsigned int u1 = f2bf(tile[cpair * 2 + 1][p]);
            *(unsigned int*)&fbuf[((size_t)((cv * 2 + b) * HW + pt * 64 + p)) * 256
                                  + cb * 64 + cpair * 2] = u0 | (u1 << 16);
        }
    } else {
        // ---- weights -> A-frag (g-major step order) ----
        // L = conv*73728 + ((s*2+kk)*16+ot)*64+lane ; g = s/9, k = s%9
        int L = (bb - 2176) * 256 + threadIdx.x;
        int conv = L / 73728;
        int r = L - conv * 73728;
        int lane = r & 63;
        int ot = (r >> 6) & 15;
        int kk = (r >> 10) & 1;
        int s  = r >> 11;
        int g = s / 9, k = s - g * 9;
        int o  = ot * 16 + (lane & 15);
        int cb = kk * 32 + (lane >> 4) * 8;
        const float* w = conv ? wc : wr;
        s16x8 v;
        #pragma unroll
        for (int j = 0; j < 8; ++j) {
            int c = cb + j;
            v[j] = (short)f2bf(w[((size_t)o * 256 + g * 64 + c) * 9 + k]);
        }
        *(s16x8*)(wfrag + (size_t)L * 8) = v;
    }
}

// ---------------------------------------------------------------------------
// K_main: fused implicit GEMM (R9 shape: 256 blocks x 512 threads, 8 waves,
// 1 block/CU; wave wv: 32 Cout x 64 px, acc[2][4]) + g-major step order.
// For 9 consecutive steps the gathers hit one g channel-slice (~43 KB working
// set) -> L1 reuse cuts the dominant L2->L1 fill traffic.
// Pipeline per iteration s:
//   issue gathers(s+2) + ldpar(s+3)  [vmcnt, ~1.5 steps in flight]
//   lgkmcnt(0) drain; raw s_barrier  [vmcnt NOT drained]
//   domfma(s)   -- pure LDS + MFMA (A-frags register-double-buffered)
//   loadA(s+1); finish(s+1) from gathers issued at s-1
// ---------------------------------------------------------------------------
__global__ void __launch_bounds__(512, 2)
k_main(const int4* __restrict__ pbuf,
       const unsigned short* __restrict__ fbuf, const unsigned short* __restrict__ wfrag,
       float* __restrict__ out) {
    __shared__ __align__(16) unsigned short vt[2][64][72];   // 64 px x 64 ch + pad

    int bid0 = blockIdx.x;
    int bid = (bid0 & 7) * 32 + (bid0 >> 3);       // XCD-contiguous swizzle (256%8==0)
    int conv = bid >> 7;
    int b    = (bid >> 6) & 1;
    int pt   = bid & 63;
    int p0   = pt * 64;

    int tid  = threadIdx.x;
    int lane = tid & 63;
    int wv   = tid >> 6;                           // wave id = Cout group (8 x 32)
    int px   = tid >> 3;                           // build: pixel 0..63
    int cg   = tid & 7;                            // build: channel granule (8 ch)

    const char* fbb = (const char*)(fbuf + (size_t)(conv * 2 + b) * HW * 256);
    const unsigned short* wfc = wfrag + (size_t)conv * 73728 * 8;
    const int4* pbb = pbuf + (size_t)b * 9 * 4 * HW + p0 + px;

    f32x4 acc[2][4];
    #pragma unroll
    for (int i = 0; i < 2; ++i)
        #pragma unroll
        for (int j = 0; j < 4; ++j)
            acc[i][j] = (f32x4){0.f, 0.f, 0.f, 0.f};

    struct Gat { s16x8 a, b, c, d; };

    auto ldpar = [&](int s) -> int4 {
        int g = s / 9, k = s - g * 9;              // g-major order
        return pbb[(k * 4 + g) * HW];
    };

    auto gather = [&](const int4& P, int g) -> Gat {
        const char* base = fbb + g * 128 + cg * 16;
        int o0 = ((unsigned)P.z & 0xffffu) << 9;
        int o1 = ((unsigned)P.z >> 16) << 9;
        int o2 = ((unsigned)P.w & 0xffffu) << 9;
        int o3 = ((unsigned)P.w >> 16) << 9;
        Gat G;
        G.a = *(const s16x8*)(base + o0);
        G.b = *(const s16x8*)(base + o1);
        G.c = *(const s16x8*)(base + o2);
        G.d = *(const s16x8*)(base + o3);
        return G;
    };

    auto finish = [&](const int4& P, const Gat& G, int buf) {
        float w0 = h2f((unsigned)P.x & 0xffffu), w1 = h2f((unsigned)P.x >> 16);
        float w2 = h2f((unsigned)P.y & 0xffffu), w3 = h2f((unsigned)P.y >> 16);
        s16x8 pk;
        #pragma unroll
        for (int j = 0; j < 8; ++j) {
            float r = w0 * bf2f((unsigned short)G.a[j])
                    + w1 * bf2f((unsigned short)G.b[j])
                    + w2 * bf2f((unsigned short)G.c[j])
                    + w3 * bf2f((unsigned short)G.d[j]);
            pk[j] = (short)f2bf(r);
        }
        *(s16x8*)&vt[buf][px][cg * 8] = pk;
    };

    // A-fragment register double-buffer: 4 frags per wave per step.
    s16x8 af00, af01, af10, af11;      // af[kk][mo]
    auto loadA = [&](int s) {
        const unsigned short* wfs = wfc + (size_t)s * 2048 * 8;
        af00 = *(const s16x8*)(wfs + ((size_t)( 0 + wv * 2 + 0) * 64 + lane) * 8);
        af01 = *(const s16x8*)(wfs + ((size_t)( 0 + wv * 2 + 1) * 64 + lane) * 8);
        af10 = *(const s16x8*)(wfs + ((size_t)(16 + wv * 2 + 0) * 64 + lane) * 8);
        af11 = *(const s16x8*)(wfs + ((size_t)(16 + wv * 2 + 1) * 64 + lane) * 8);
    };

    auto domfma = [&](int s) {
        s16x8 bfr[4];
        #pragma unroll
        for (int np = 0; np < 4; ++np)
            bfr[np] = *(const s16x8*)
                &vt[s & 1][np * 16 + (lane & 15)][(lane >> 4) * 8];          // kk=0
        #pragma unroll
        for (int np = 0; np < 4; ++np)
            acc[0][np] = __builtin_amdgcn_mfma_f32_16x16x32_bf16(af00, bfr[np],
                                                                 acc[0][np], 0, 0, 0);
        #pragma unroll
        for (int np = 0; np < 4; ++np)
            acc[1][np] = __builtin_amdgcn_mfma_f32_16x16x32_bf16(af01, bfr[np],
                                                                 acc[1][np], 0, 0, 0);
        #pragma unroll
        for (int np = 0; np < 4; ++np)
            bfr[np] = *(const s16x8*)
                &vt[s & 1][np * 16 + (lane & 15)][32 + (lane >> 4) * 8];     // kk=1
        #pragma unroll
        for (int np = 0; np < 4; ++np)
            acc[0][np] = __builtin_amdgcn_mfma_f32_16x16x32_bf16(af10, bfr[np],
                                                                 acc[0][np], 0, 0, 0);
        #pragma unroll
        for (int np = 0; np < 4; ++np)
            acc[1][np] = __builtin_amdgcn_mfma_f32_16x16x32_bf16(af11, bfr[np],
                                                                 acc[1][np], 0, 0, 0);
    };

    // ---- software pipeline (gathers 2 steps deep) ----
    loadA(0);
    int4 P0 = ldpar(0);
    Gat G0 = gather(P0, 0);             // step 0: g=0
    finish(P0, G0, 0);                  // vt[0]
    int4 P1 = ldpar(1);                 // par(s+1)
    int4 P2 = ldpar(2);                 // par(s+2)
    Gat G1 = gather(P1, 0);             // step 1: g = 1/9 = 0

    for (int s = 0; s < 36; ++s) {
        Gat Gn;                          // gathers for step s+2
        int4 Pn;
        if (s + 2 < 36) Gn = gather(P2, (s + 2) / 9);
        Pn = (s + 3 < 36) ? ldpar(s + 3) : P2;
        asm volatile("s_waitcnt lgkmcnt(0)" ::: "memory"); // vt writes visible
        __builtin_amdgcn_s_barrier();                      // vmcnt NOT drained
        domfma(s);                       // pure LDS + MFMA (af prefetched)
        if (s + 1 < 36) {
            loadA(s + 1);                // af used by domfma(s) already
            finish(P1, G1, (s + 1) & 1); // G1 issued at iter s-1: landed
        }
        P1 = P2; P2 = Pn; G1 = Gn;
    }

    // epilogue: C/D layout col = lane&15 (pixel), row = (lane>>4)*4 + reg (o)
    float* ob = out + (size_t)conv * (NB * 256 * HW) + (size_t)b * 256 * HW;
    #pragma unroll
    for (int mo = 0; mo < 2; ++mo)
        #pragma unroll
        for (int np = 0; np < 4; ++np)
            #pragma unroll
            for (int r = 0; r < 4; ++r) {
                int o = wv * 32 + mo * 16 + (lane >> 4) * 4 + r;
                int p = p0 + np * 16 + (lane & 15);
                float v = acc[mo][np][r];
                ob[(size_t)o * HW + p] = v > 0.f ? v : 0.f;
            }
}

// ---------------------------------------------------------------------------
// ws layout (bytes):
//   [0,        4718592)  pbuf  : 294912 int4 (packed params)
//   [4718592, 13107200)  fbuf  : 4*4096*256 bf16 NHWC
//   [13107200,15466496)  wfrag : 2*73728*8 bf16
// requires ws_size >= 15466496
// ---------------------------------------------------------------------------
extern "C" void kernel_launch(void* const* d_in, const int* in_sizes, int n_in,
                              void* d_out, int out_size, void* d_ws, size_t ws_size,
                              hipStream_t stream) {
    (void)in_sizes; (void)n_in; (void)out_size; (void)ws_size;
    const float* reg_feat = (const float*)d_in[0];
    const float* cls_feat = (const float*)d_in[1];
    const float* pred     = (const float*)d_in[2];
    const float* w_off    = (const float*)d_in[3];
    const float* w_reg    = (const float*)d_in[4];
    const float* w_cls    = (const float*)d_in[5];
    float* out = (float*)d_out;
    char* ws = (char*)d_ws;
    int4*           pbuf  = (int4*)ws;
    unsigned short* fbuf  = (unsigned short*)(ws + 4718592);
    unsigned short* wfrag = (unsigned short*)(ws + 13107200);

    k_prep<<<2752, 256, 0, stream>>>(pred, w_off, reg_feat, cls_feat, w_reg, w_cls,
                                     pbuf, fbuf, wfrag);
    k_main<<< 256, 512, 0, stream>>>(pbuf, fbuf, wfrag, out);
}

// Round 13
// 49.958 us; speedup vs baseline: 1.2503x; 1.0017x over previous
//
#include <hip/hip_runtime.h>
#include <hip/hip_bf16.h>
#include <stdint.h>

// Problem constants (fixed by setup_inputs): B=2, C=256, H=W=64, dg=4, K=3x3.
#define HW   4096
#define NB   2

typedef float f32x4 __attribute__((ext_vector_type(4)));
typedef float f32x2 __attribute__((ext_vector_type(2)));
typedef short s16x8 __attribute__((ext_vector_type(8)));

__device__ __forceinline__ unsigned short f2bf(float f) {
    // round-to-nearest-even f32 -> bf16
    union { float f; unsigned int u; } v; v.f = f;
    unsigned int u = v.u;
    unsigned int r = (u + 0x7FFFu + ((u >> 16) & 1u)) >> 16;
    return (unsigned short)r;
}

__device__ __forceinline__ float bf2f(unsigned short u) {
    union { unsigned int u; float f; } v; v.u = ((unsigned int)u) << 16;
    return v.f;
}

// unpack a dword of 2 bf16 -> f32x2 (2 ops: shl, and-hi)
__device__ __forceinline__ f32x2 unpk(unsigned int dw) {
    union { unsigned int u; float f; } lo, hi;
    lo.u = dw << 16;
    hi.u = dw & 0xffff0000u;
    return (f32x2){lo.f, hi.f};
}

// Step order (g-major, R12-proven): 9 consecutive steps share one g slice
// (L1 reuse of the gather working set). g = s/9, k = s%9.

// ---------------------------------------------------------------------------
// K_prep: three independent prep stages in ONE dispatch.
//   blocks [0,1152)     : offset 1x1 conv + bilinear setup -> PACKED 16B params
//                         pbuf[loc] = {bf16 w0..w3 | u16 row0..row3}   (R13: bf16)
//   blocks [1152,2176)  : NCHW f32 -> NHWC bf16 transpose (R13: vectorized)
//   blocks [2176,2752)  : weights -> bf16 MFMA A-frag order (wfrag, g-major s)
// ---------------------------------------------------------------------------
__global__ void __launch_bounds__(256)
k_prep(const float* __restrict__ pred, const float* __restrict__ wo,
       const float* __restrict__ regf, const float* __restrict__ clsf,
       const float* __restrict__ wr,   const float* __restrict__ wc,
       int4* __restrict__ pbuf,
       unsigned short* __restrict__ fbuf, unsigned short* __restrict__ wfrag) {
    int bb = blockIdx.x;
    if (bb < 1152) {
        // ---- params: loc = ((b*9+k)*4+g)*4096 + p ----
        int loc = bb * 256 + threadIdx.x;
        int p  = loc & 4095;
        int g  = (loc >> 12) & 3;
        int bk = loc >> 14;
        int b  = bk / 9;
        int k  = bk - b * 9;
        int rowy = ((g * 9 + k) * 2) * 34;
        float oy = 0.f, ox = 0.f;
        const float* pb = pred + (size_t)b * 34 * HW + p;
        #pragma unroll
        for (int c = 0; c < 34; ++c) {
            float pv = pb[c * HW];
            oy += wo[rowy + c]      * pv;
            ox += wo[rowy + 34 + c] * pv;
        }
        int h = p >> 6, w = p & 63;
        int ky = k / 3, kx = k - ky * 3;
        float py = oy + (float)(h + ky - 1);
        float px = ox + (float)(w + kx - 1);
        float fy0 = floorf(py), fx0 = floorf(px);
        int y0 = (int)fy0, x0 = (int)fx0;
        float fy = py - fy0, fx = px - fx0;
        float wy0 = 1.f - fy, wy1 = fy, wx0 = 1.f - fx, wx1 = fx;
        if (!(y0 >= 0  && y0 <= 63)) wy0 = 0.f;
        if (!(y0 >= -1 && y0 <= 62)) wy1 = 0.f;
        if (!(x0 >= 0  && x0 <= 63)) wx0 = 0.f;
        if (!(x0 >= -1 && x0 <= 62)) wx1 = 0.f;
        int cy0 = min(max(y0, 0), 63),     cy1 = min(max(y0 + 1, 0), 63);
        int cx0 = min(max(x0, 0), 63),     cx1 = min(max(x0 + 1, 0), 63);
        int r0 = cy0 * 64 + cx0, r1 = cy0 * 64 + cx1;
        int r2 = cy1 * 64 + cx0, r3 = cy1 * 64 + cx1;
        int4 pk;
        pk.x = (int)((unsigned)f2bf(wy0 * wx0) | ((unsigned)f2bf(wy0 * wx1) << 16));
        pk.y = (int)((unsigned)f2bf(wy1 * wx0) | ((unsigned)f2bf(wy1 * wx1) << 16));
        pk.z = (int)((unsigned)r0 | ((unsigned)r1 << 16));
        pk.w = (int)((unsigned)r2 | ((unsigned)r3 << 16));
        pbuf[loc] = pk;
    } else if (bb < 2176) {
        // ---- NCHW f32 -> NHWC bf16 (vectorized: float4 loads, uint2 stores) ----
        __shared__ float tile[64][65];
        int bid = bb - 1152;
        int pt = bid & 63;
        int cb = (bid >> 6) & 3;
        int b  = (bid >> 8) & 1;
        int cv = bid >> 9;
        const float* src = cv ? clsf : regf;
        int t = threadIdx.x;
        int cl = t >> 2, q = t & 3;                // row cl, column-quad q
        #pragma unroll
        for (int i = 0; i < 4; ++i) {
            float4 v = *(const float4*)&src[((size_t)(b * 256 + cb * 64 + cl)) * HW
                                            + pt * 64 + q * 16 + i * 4];
            tile[cl][q * 16 + i * 4 + 0] = v.x;
            tile[cl][q * 16 + i * 4 + 1] = v.y;
            tile[cl][q * 16 + i * 4 + 2] = v.z;
            tile[cl][q * 16 + i * 4 + 3] = v.w;
        }
        __syncthreads();
        int c4 = t & 15, pr = t >> 4;              // 4-ch group, pixel row
        #pragma unroll
        for (int i = 0; i < 4; ++i) {
            int p = i * 16 + pr;
            unsigned int u0 = (unsigned)f2bf(tile[c4 * 4 + 0][p])
                            | ((unsigned)f2bf(tile[c4 * 4 + 1][p]) << 16);
            unsigned int u1 = (unsigned)f2bf(tile[c4 * 4 + 2][p])
                            | ((unsigned)f2bf(tile[c4 * 4 + 3][p]) << 16);
            uint2 u; u.x = u0; u.y = u1;
            *(uint2*)&fbuf[((size_t)((cv * 2 + b) * HW + pt * 64 + p)) * 256
                           + cb * 64 + c4 * 4] = u;
        }
    } else {
        // ---- weights -> A-frag (g-major step order) ----
        // L = conv*73728 + ((s*2+kk)*16+ot)*64+lane ; g = s/9, k = s%9
        int L = (bb - 2176) * 256 + threadIdx.x;
        int conv = L / 73728;
        int r = L - conv * 73728;
        int lane = r & 63;
        int ot = (r >> 6) & 15;
        int kk = (r >> 10) & 1;
        int s  = r >> 11;
        int g = s / 9, k = s - g * 9;
        int o  = ot * 16 + (lane & 15);
        int cb = kk * 32 + (lane >> 4) * 8;
        const float* w = conv ? wc : wr;
        s16x8 v;
        #pragma unroll
        for (int j = 0; j < 8; ++j) {
            int c = cb + j;
            v[j] = (short)f2bf(w[((size_t)o * 256 + g * 64 + c) * 9 + k]);
        }
        *(s16x8*)(wfrag + (size_t)L * 8) = v;
    }
}

// ---------------------------------------------------------------------------
// K_main: fused implicit GEMM (R12 structure: 256 blocks x 512 threads, 8
// waves, 1 block/CU; wave wv: 32 Cout x 64 px, acc[2][4]; g-major steps).
// R13: finish lerp in f32x2 (v_pk_fma_f32) with bf16-packed weights.
// Pipeline per iteration s:
//   issue gathers(s+2) + ldpar(s+3)  [vmcnt, ~1.5 steps in flight]
//   lgkmcnt(0) drain; raw s_barrier  [vmcnt NOT drained]
//   domfma(s)   -- pure LDS + MFMA (A-frags register-double-buffered)
//   loadA(s+1); finish(s+1) from gathers issued at s-1
// ---------------------------------------------------------------------------
__global__ void __launch_bounds__(512, 2)
k_main(const int4* __restrict__ pbuf,
       const unsigned short* __restrict__ fbuf, const unsigned short* __restrict__ wfrag,
       float* __restrict__ out) {
    __shared__ __align__(16) unsigned short vt[2][64][72];   // 64 px x 64 ch + pad

    int bid0 = blockIdx.x;
    int bid = (bid0 & 7) * 32 + (bid0 >> 3);       // XCD-contiguous swizzle (256%8==0)
    int conv = bid >> 7;
    int b    = (bid >> 6) & 1;
    int pt   = bid & 63;
    int p0   = pt * 64;

    int tid  = threadIdx.x;
    int lane = tid & 63;
    int wv   = tid >> 6;                           // wave id = Cout group (8 x 32)
    int px   = tid >> 3;                           // build: pixel 0..63
    int cg   = tid & 7;                            // build: channel granule (8 ch)

    const char* fbb = (const char*)(fbuf + (size_t)(conv * 2 + b) * HW * 256);
    const unsigned short* wfc = wfrag + (size_t)conv * 73728 * 8;
    const int4* pbb = pbuf + (size_t)b * 9 * 4 * HW + p0 + px;

    f32x4 acc[2][4];
    #pragma unroll
    for (int i = 0; i < 2; ++i)
        #pragma unroll
        for (int j = 0; j < 4; ++j)
            acc[i][j] = (f32x4){0.f, 0.f, 0.f, 0.f};

    union G8 { s16x8 v; unsigned int u[4]; };
    struct Gat { G8 a, b, c, d; };

    auto ldpar = [&](int s) -> int4 {
        int g = s / 9, k = s - g * 9;              // g-major order
        return pbb[(k * 4 + g) * HW];
    };

    auto gather = [&](const int4& P, int g) -> Gat {
        const char* base = fbb + g * 128 + cg * 16;
        int o0 = ((unsigned)P.z & 0xffffu) << 9;
        int o1 = ((unsigned)P.z >> 16) << 9;
        int o2 = ((unsigned)P.w & 0xffffu) << 9;
        int o3 = ((unsigned)P.w >> 16) << 9;
        Gat G;
        G.a.v = *(const s16x8*)(base + o0);
        G.b.v = *(const s16x8*)(base + o1);
        G.c.v = *(const s16x8*)(base + o2);
        G.d.v = *(const s16x8*)(base + o3);
        return G;
    };

    auto finish = [&](const int4& P, const Gat& G, int buf) {
        float w0 = bf2f((unsigned short)((unsigned)P.x & 0xffffu));
        float w1 = bf2f((unsigned short)((unsigned)P.x >> 16));
        float w2 = bf2f((unsigned short)((unsigned)P.y & 0xffffu));
        float w3 = bf2f((unsigned short)((unsigned)P.y >> 16));
        s16x8 pk;
        #pragma unroll
        for (int i = 0; i < 4; ++i) {
            f32x2 r = unpk(G.a.u[i]) * w0 + unpk(G.b.u[i]) * w1
                    + unpk(G.c.u[i]) * w2 + unpk(G.d.u[i]) * w3;
            pk[2 * i]     = (short)f2bf(r.x);
            pk[2 * i + 1] = (short)f2bf(r.y);
        }
        *(s16x8*)&vt[buf][px][cg * 8] = pk;
    };

    // A-fragment register double-buffer: 4 frags per wave per step.
    s16x8 af00, af01, af10, af11;      // af[kk][mo]
    auto loadA = [&](int s) {
        const unsigned short* wfs = wfc + (size_t)s * 2048 * 8;
        af00 = *(const s16x8*)(wfs + ((size_t)( 0 + wv * 2 + 0) * 64 + lane) * 8);
        af01 = *(const s16x8*)(wfs + ((size_t)( 0 + wv * 2 + 1) * 64 + lane) * 8);
        af10 = *(const s16x8*)(wfs + ((size_t)(16 + wv * 2 + 0) * 64 + lane) * 8);
        af11 = *(const s16x8*)(wfs + ((size_t)(16 + wv * 2 + 1) * 64 + lane) * 8);
    };

    auto domfma = [&](int s) {
        s16x8 bfr[4];
        #pragma unroll
        for (int np = 0; np < 4; ++np)
            bfr[np] = *(const s16x8*)
                &vt[s & 1][np * 16 + (lane & 15)][(lane >> 4) * 8];          // kk=0
        #pragma unroll
        for (int np = 0; np < 4; ++np)
            acc[0][np] = __builtin_amdgcn_mfma_f32_16x16x32_bf16(af00, bfr[np],
                                                                 acc[0][np], 0, 0, 0);
        #pragma unroll
        for (int np = 0; np < 4; ++np)
            acc[1][np] = __builtin_amdgcn_mfma_f32_16x16x32_bf16(af01, bfr[np],
                                                                 acc[1][np], 0, 0, 0);
        #pragma unroll
        for (int np = 0; np < 4; ++np)
            bfr[np] = *(const s16x8*)
                &vt[s & 1][np * 16 + (lane & 15)][32 + (lane >> 4) * 8];     // kk=1
        #pragma unroll
        for (int np = 0; np < 4; ++np)
            acc[0][np] = __builtin_amdgcn_mfma_f32_16x16x32_bf16(af10, bfr[np],
                                                                 acc[0][np], 0, 0, 0);
        #pragma unroll
        for (int np = 0; np < 4; ++np)
            acc[1][np] = __builtin_amdgcn_mfma_f32_16x16x32_bf16(af11, bfr[np],
                                                                 acc[1][np], 0, 0, 0);
    };

    // ---- software pipeline (gathers 2 steps deep) ----
    loadA(0);
    int4 P0 = ldpar(0);
    Gat G0 = gather(P0, 0);             // step 0: g=0
    finish(P0, G0, 0);                  // vt[0]
    int4 P1 = ldpar(1);                 // par(s+1)
    int4 P2 = ldpar(2);                 // par(s+2)
    Gat G1 = gather(P1, 0);             // step 1: g = 1/9 = 0

    for (int s = 0; s < 36; ++s) {
        Gat Gn;                          // gathers for step s+2
        int4 Pn;
        if (s + 2 < 36) Gn = gather(P2, (s + 2) / 9);
        Pn = (s + 3 < 36) ? ldpar(s + 3) : P2;
        asm volatile("s_waitcnt lgkmcnt(0)" ::: "memory"); // vt writes visible
        __builtin_amdgcn_s_barrier();                      // vmcnt NOT drained
        domfma(s);                       // pure LDS + MFMA (af prefetched)
        if (s + 1 < 36) {
            loadA(s + 1);                // af used by domfma(s) already
            finish(P1, G1, (s + 1) & 1); // G1 issued at iter s-1: landed
        }
        P1 = P2; P2 = Pn; G1 = Gn;
    }

    // epilogue: C/D layout col = lane&15 (pixel), row = (lane>>4)*4 + reg (o)
    float* ob = out + (size_t)conv * (NB * 256 * HW) + (size_t)b * 256 * HW;
    #pragma unroll
    for (int mo = 0; mo < 2; ++mo)
        #pragma unroll
        for (int np = 0; np < 4; ++np)
            #pragma unroll
            for (int r = 0; r < 4; ++r) {
                int o = wv * 32 + mo * 16 + (lane >> 4) * 4 + r;
                int p = p0 + np * 16 + (lane & 15);
                float v = acc[mo][np][r];
                ob[(size_t)o * HW + p] = v > 0.f ? v : 0.f;
            }
}

// ---------------------------------------------------------------------------
// ws layout (bytes):
//   [0,        4718592)  pbuf  : 294912 int4 (packed params, bf16 weights)
//   [4718592, 13107200)  fbuf  : 4*4096*256 bf16 NHWC
//   [13107200,15466496)  wfrag : 2*73728*8 bf16
// requires ws_size >= 15466496
// ---------------------------------------------------------------------------
extern "C" void kernel_launch(void* const* d_in, const int* in_sizes, int n_in,
                              void* d_out, int out_size, void* d_ws, size_t ws_size,
                              hipStream_t stream) {
    (void)in_sizes; (void)n_in; (void)out_size; (void)ws_size;
    const float* reg_feat = (const float*)d_in[0];
    const float* cls_feat = (const float*)d_in[1];
    const float* pred     = (const float*)d_in[2];
    const float* w_off    = (const float*)d_in[3];
    const float* w_reg    = (const float*)d_in[4];
    const float* w_cls    = (const float*)d_in[5];
    float* out = (float*)d_out;
    char* ws = (char*)d_ws;
    int4*           pbuf  = (int4*)ws;
    unsigned short* fbuf  = (unsigned short*)(ws + 4718592);
    unsigned short* wfrag = (unsigned short*)(ws + 13107200);

    k_prep<<<2752, 256, 0, stream>>>(pred, w_off, reg_feat, cls_feat, w_reg, w_cls,
                                     pbuf, fbuf, wfrag);
    k_main<<< 256, 512, 0, stream>>>(pbuf, fbuf, wfrag, out);
}